// Round 7
// baseline (409.883 us; speedup 1.0000x reference)
//
#include <hip/hip_runtime.h>
#include <hip/hip_bf16.h>
#include <math.h>

#define F 128
#define NBLK 256      // blocks for bucket_count / bucket_scatter
#define MAXNB 2048    // max buckets (N up to 131072 at 64 nodes/bucket)
#define CMASK 0x03FFFFFFu   // col payload mask (src id); bits 26..31 = tile-local dst

typedef short bf16x8 __attribute__((ext_vector_type(8)));
typedef float f32x4 __attribute__((ext_vector_type(4)));
typedef float f32x2 __attribute__((ext_vector_type(2)));

__device__ __forceinline__ int rfl(int v) { return __builtin_amdgcn_readfirstlane(v); }
__device__ __forceinline__ unsigned short f2bf(float f) {
    __hip_bfloat16 h = __float2bfloat16(f);
    return *reinterpret_cast<unsigned short*>(&h);
}
__device__ __forceinline__ unsigned pack2(float lo, float hi) {
    return (unsigned)f2bf(lo) | ((unsigned)f2bf(hi) << 16);
}

// ---------------- CSR build via counting sort (zero global atomics) ----------------

// K1: per-(block,bucket) histogram. Block b owns contiguous edge chunk.
__global__ __launch_bounds__(256) void bucket_count(
    const int* __restrict__ dst, int E, int NB, int chunk, int* __restrict__ hist2)
{
    __shared__ int h[MAXNB];
    for (int j = threadIdx.x; j < NB; j += 256) h[j] = 0;
    __syncthreads();
    int b = blockIdx.x;
    int beg = b * chunk, end = min(E, beg + chunk);
    for (int e = beg + threadIdx.x; e < end; e += 256)
        atomicAdd(&h[dst[e] >> 6], 1);             // LDS atomic
    __syncthreads();
    for (int j = threadIdx.x; j < NB; j += 256) hist2[b * NB + j] = h[j];
}

// K2: bucket bases (col-space incl self-loops, pair-space) + per-(block,bucket) bases.
__global__ __launch_bounds__(1024) void bucket_scan(
    int* __restrict__ hist2, int NB, int N,
    int* __restrict__ colbase, int* __restrict__ pairbase)
{
    __shared__ int ct[MAXNB], pt[MAXNB];
    int t = threadIdx.x;
    for (int j = t; j < MAXNB; j += 1024) { ct[j] = 0; pt[j] = 0; }
    __syncthreads();
    for (int j = t; j < NB; j += 1024) {
        int tot = 0;
        for (int b = 0; b < NBLK; ++b) tot += hist2[b * NB + j];
        int n0 = j << 6;
        int nodes = (n0 + 64 <= N) ? 64 : (N - n0);
        pt[j] = tot;
        ct[j] = tot + nodes;
    }
    __syncthreads();
    for (int off = 1; off < MAXNB; off <<= 1) {
        int i0 = t, i1 = t + 1024;
        int a0 = (i0 >= off) ? ct[i0 - off] : 0;
        int b0 = (i0 >= off) ? pt[i0 - off] : 0;
        int a1 = ct[i1 - off];
        int b1 = pt[i1 - off];
        __syncthreads();
        ct[i0] += a0; pt[i0] += b0;
        ct[i1] += a1; pt[i1] += b1;
        __syncthreads();
    }
    for (int j = t; j < NB; j += 1024) {
        colbase[j]  = j ? ct[j - 1] : 0;
        pairbase[j] = j ? pt[j - 1] : 0;
    }
    if (t == 0) { colbase[NB] = ct[NB - 1]; pairbase[NB] = pt[NB - 1]; }
    __syncthreads();
    for (int j = t; j < NB; j += 1024) {
        int run = j ? pt[j - 1] : 0;
        for (int b = 0; b < NBLK; ++b) {
            int c = hist2[b * NB + j];
            hist2[b * NB + j] = run;
            run += c;
        }
    }
}

// K3: scatter (src,dst) into bucket regions; ranks via LDS atomics only.
__global__ __launch_bounds__(256) void bucket_scatter(
    const int* __restrict__ src, const int* __restrict__ dst, int E, int NB, int chunk,
    const int* __restrict__ gbase2, uint2* __restrict__ pairs)
{
    __shared__ int ofs[MAXNB];
    int b = blockIdx.x;
    for (int j = threadIdx.x; j < NB; j += 256) ofs[j] = gbase2[b * NB + j];
    __syncthreads();
    int beg = b * chunk, end = min(E, beg + chunk);
    for (int e = beg + threadIdx.x; e < end; e += 256) {
        int s = src[e], d = dst[e];
        int slot = atomicAdd(&ofs[d >> 6], 1);     // LDS atomic
        pairs[slot] = make_uint2((unsigned)s, (unsigned)d);
    }
}

// K4: per-bucket node-CSR: rp, dinv, self-loop, col scatter.
// col entries carry tile-local dst in bits 26..31.
__global__ __launch_bounds__(256) void bucket_csr(
    const uint2* __restrict__ pairs, const int* __restrict__ pairbase,
    const int* __restrict__ colbase, int N, int E,
    int* __restrict__ rp, int* __restrict__ col, float* __restrict__ dinv)
{
    __shared__ int cnt[64], fill[64], seg[64];
    int j = blockIdx.x;
    int t = threadIdx.x;
    if (t < 64) { cnt[t] = 0; fill[t] = 0; }
    __syncthreads();
    int beg = pairbase[j], end = pairbase[j + 1];
    int n0 = j << 6;
    for (int e = beg + t; e < end; e += 256)
        atomicAdd(&cnt[pairs[e].y & 63], 1);
    __syncthreads();
    if (t < 64) {
        int c = cnt[t];
        int v = c + 1;                 // + self-loop
#pragma unroll
        for (int off = 1; off < 64; off <<= 1) {
            int u = __shfl_up(v, off);
            if (t >= off) v += u;
        }
        int segb = colbase[j] + v - (c + 1);   // exclusive scan base
        int n = n0 + t;
        if (n < N) {
            seg[t] = segb;
            rp[n] = segb;
            dinv[n] = rsqrtf((float)(c + 1));
            col[segb + c] = n | (t << 26);     // tagged self-loop at segment end
            if (n == N - 1) rp[N] = segb + c + 1;
        }
    }
    __syncthreads();
    for (int e = beg + t; e < end; e += 256) {
        uint2 pr = pairs[e];
        int ln = (int)(pr.y & 63);
        int r = atomicAdd(&fill[ln], 1);       // LDS atomic
        col[seg[ln] + r] = (int)pr.x | (ln << 26);
    }
}

// ------- W1 -> bf16, transposed [j][k], XOR-swizzled bytes (once) -------
__global__ void w1prep(const float* __restrict__ W1, unsigned char* __restrict__ W1t) {
    int tid = blockIdx.x * blockDim.x + threadIdx.x;   // tid = j*128 + k
    if (tid >= F * F) return;
    int j = tid >> 7, k = tid & 127;
    unsigned short w = f2bf(W1[k * F + j]);
    int ofs = (j << 8) + (((k << 1)) ^ ((j & 7) << 4));
    *reinterpret_cast<unsigned short*>(W1t + ofs) = w;
}

// ------- prescale: xsq[p][n][32] = fp8(dinv[n]*x[n][32p..32p+31]) -------
__global__ void prescale(const float* __restrict__ x, const float* __restrict__ dinv,
                         unsigned char* __restrict__ xsq, int N) {
    int i = blockIdx.x * blockDim.x + threadIdx.x;   // float4 group: n*32+g
    if (i >= N * 32) return;
    int n = i >> 5, g = i & 31;
    int p = g >> 3, q = g & 7;
    float d = dinv[n];
    float4 v = ((const float4*)x)[i];
    int r = __builtin_amdgcn_cvt_pk_fp8_f32(v.x * d, v.y * d, 0, false);
    r = __builtin_amdgcn_cvt_pk_fp8_f32(v.z * d, v.w * d, r, true);
    *reinterpret_cast<unsigned*>(xsq + (size_t)p * N * 32 + (size_t)n * 32 + 4 * q) = r;
}

// ------- agg1 v3: edge-centric, per-octet register acc, LDS tile accumulator -------
// Pass p owns a 3.2MB xsq quarter (L2-resident). Block owns a 64-node tile.
// 32 octets split the tile's contiguous edge range; flush to LDS on node change.
__global__ __launch_bounds__(256) void agg1(
    const unsigned char* __restrict__ xsq, const int* __restrict__ rp,
    const int* __restrict__ col, const float* __restrict__ dinv,
    unsigned short* __restrict__ xa, int N, int ntiles)
{
    __shared__ float acc[64 * 33];       // +1 f32 pad per node: kills bank alias
    int p = blockIdx.x / ntiles;
    int tile = blockIdx.x - p * ntiles;
    int n0 = tile << 6;
    int nodes = min(64, N - n0);
    const unsigned char* xsp = xsq + (size_t)p * N * 32;

    for (int i = threadIdx.x; i < 64 * 33; i += 256) acc[i] = 0.f;
    __syncthreads();

    int ebase = rfl(rp[n0]);
    int eend  = rfl(rp[min(n0 + 64, N)]);
    int elen  = eend - ebase;
    int q = threadIdx.x >> 3, c8 = threadIdx.x & 7;
    int e0 = ebase + (elen * q) / 32;
    int e1 = ebase + (elen * (q + 1)) / 32;

    if (e0 < e1) {
        int cur = ((unsigned)col[e0]) >> 26;
        f32x2 a0 = {0.f, 0.f}, a1 = {0.f, 0.f};
        for (int e = e0; e < e1; ++e) {
            unsigned cv = (unsigned)col[e];
            int nd = (int)(cv >> 26);
            if (nd != cur) {
                int b = cur * 33 + 4 * c8;
                atomicAdd(&acc[b + 0], a0.x);
                atomicAdd(&acc[b + 1], a0.y);
                atomicAdd(&acc[b + 2], a1.x);
                atomicAdd(&acc[b + 3], a1.y);
                a0 = {0.f, 0.f}; a1 = {0.f, 0.f};
                cur = nd;
            }
            unsigned s = cv & CMASK;
            unsigned u = *reinterpret_cast<const unsigned*>(xsp + (size_t)s * 32 + 4 * c8);
            a0 += __builtin_amdgcn_cvt_pk_f32_fp8(u, false);
            a1 += __builtin_amdgcn_cvt_pk_f32_fp8(u, true);
        }
        int b = cur * 33 + 4 * c8;
        atomicAdd(&acc[b + 0], a0.x);
        atomicAdd(&acc[b + 1], a0.y);
        atomicAdd(&acc[b + 2], a1.x);
        atomicAdd(&acc[b + 3], a1.y);
    }
    __syncthreads();

    // epilogue: thread t -> node t>>2, 8 feats; scale by dinv, pack bf16, 16B store
    int nd = threadIdx.x >> 2, fq = threadIdx.x & 3;
    if (nd < nodes) {
        float d = dinv[n0 + nd];
        const float* ap = &acc[nd * 33 + 8 * fq];
        unsigned u0 = pack2(ap[0] * d, ap[1] * d);
        unsigned u1 = pack2(ap[2] * d, ap[3] * d);
        unsigned u2 = pack2(ap[4] * d, ap[5] * d);
        unsigned u3 = pack2(ap[6] * d, ap[7] * d);
        *reinterpret_cast<uint4*>(xa + (size_t)(n0 + nd) * F + p * 32 + 8 * fq) =
            make_uint4(u0, u1, u2, u3);
    }
}

// ------- MLP: h2s[i] = dinv_i * (relu(xa@W1 + b1) @ W2) via MFMA -------
__global__ __launch_bounds__(512) void mlp(
    const unsigned short* __restrict__ xa, const float* __restrict__ dinv,
    const float* __restrict__ b1, const float* __restrict__ W2,
    const unsigned char* __restrict__ W1t_g, float* __restrict__ h2s, int N)
{
    __shared__ unsigned char W1t[F * F * 2];   // 32 KB swizzled [j][k]
    __shared__ unsigned char XA[32 * 256];     // 8 KB swizzled [node][k]
    __shared__ float part[2][16][4];

    for (int idx = threadIdx.x; idx < (F * F * 2) / 16; idx += 512)
        ((int4*)W1t)[idx] = ((const int4*)W1t_g)[idx];

    {
        int r = threadIdx.x >> 4, t16 = threadIdx.x & 15;
        int gi = blockIdx.x * 32 + r;
        uint4 v = make_uint4(0, 0, 0, 0);
        if (gi < N) v = *reinterpret_cast<const uint4*>(xa + (size_t)gi * F + 8 * t16);
        *reinterpret_cast<uint4*>(XA + r * 256 + ((16 * t16) ^ ((r & 7) << 4))) = v;
    }
    __syncthreads();

    int wave = threadIdx.x >> 6, lane = threadIdx.x & 63;
    int g = wave >> 2, jt0 = (wave & 3) * 2;
    int l15 = lane & 15;
    int kb = (lane >> 4) * 16;

    bf16x8 afr[4];
    int arow = g * 16 + l15;
#pragma unroll
    for (int kk = 0; kk < 4; ++kk) {
        int ofs = arow * 256 + ((kk * 64 + kb) ^ ((arow & 7) << 4));
        afr[kk] = *reinterpret_cast<const bf16x8*>(XA + ofs);
    }

    float p[4] = {0.f, 0.f, 0.f, 0.f};
#pragma unroll
    for (int jj = 0; jj < 2; ++jj) {
        int j = (jt0 + jj) * 16 + l15;
        f32x4 d = {0.f, 0.f, 0.f, 0.f};
#pragma unroll
        for (int kk = 0; kk < 4; ++kk) {
            int ofs = j * 256 + ((kk * 64 + kb) ^ ((j & 7) << 4));
            bf16x8 bfr = *reinterpret_cast<const bf16x8*>(W1t + ofs);
            d = __builtin_amdgcn_mfma_f32_16x16x32_bf16(afr[kk], bfr, d, 0, 0, 0);
        }
        float bj = b1[j], wj = W2[j];
#pragma unroll
        for (int r = 0; r < 4; ++r) {
            float v = fmaxf(d[r] + bj, 0.f);
            p[r] += v * wj;
        }
    }
#pragma unroll
    for (int r = 0; r < 4; ++r) {
        p[r] += __shfl_xor(p[r], 1);
        p[r] += __shfl_xor(p[r], 2);
        p[r] += __shfl_xor(p[r], 4);
        p[r] += __shfl_xor(p[r], 8);
    }
    if (l15 == 0) {
#pragma unroll
        for (int r = 0; r < 4; ++r)
            part[g][(lane >> 4) * 4 + r][wave & 3] = p[r];
    }
    __syncthreads();

    if (threadIdx.x < 32) {
        int i = blockIdx.x * 32 + threadIdx.x;
        if (i < N) {
            const float* q = part[threadIdx.x >> 4][threadIdx.x & 15];
            h2s[i] = dinv[i] * (q[0] + q[1] + q[2] + q[3]);
        }
    }
}

// ------- layer 2 aggregation: quarter-wave (16 lanes) per node -------
__global__ __launch_bounds__(256) void agg2(
    const float* __restrict__ h2s, const int* __restrict__ rp,
    const int* __restrict__ col, const float* __restrict__ dinv,
    const float* __restrict__ b2, float* __restrict__ h2, int N)
{
    int nid = (blockIdx.x * 256 + threadIdx.x) >> 4;
    int c = threadIdx.x & 15;
    if (nid >= N) return;
    int beg = rfl(rp[nid]);
    int end = rfl(rp[nid + 1]);
    float s = 0.f;
    for (int e = beg + c; e < end; e += 16)
        s += h2s[col[e] & CMASK];
#pragma unroll
    for (int off = 8; off; off >>= 1) s += __shfl_xor(s, off);
    if (c == 0) h2[nid] = dinv[nid] * s + b2[0];
}

// ------- edge probabilities -------
__global__ void edge_probs(const int* __restrict__ src, const int* __restrict__ dst,
                           const float* __restrict__ h2, float* __restrict__ out, int E) {
    int e = blockIdx.x * blockDim.x + threadIdx.x;
    if (e >= E) return;
    float v = h2[src[e]] * h2[dst[e]];
    out[e] = 1.0f / (1.0f + __expf(-v));
}

// ---------------- launch ----------------

extern "C" void kernel_launch(void* const* d_in, const int* in_sizes, int n_in,
                              void* d_out, int out_size, void* d_ws, size_t ws_size,
                              hipStream_t stream) {
    const float* x  = (const float*)d_in[0];
    const int*   ei = (const int*)d_in[1];       // int32 (JAX x64 disabled)
    const float* W1 = (const float*)d_in[2];
    const float* b1 = (const float*)d_in[3];
    const float* W2 = (const float*)d_in[4];
    const float* b2 = (const float*)d_in[5];
    float* out = (float*)d_out;

    int N = in_sizes[0] / F;
    int E = in_sizes[1] / 2;
    const int* src = ei;
    const int* dst = ei + E;
    int total = E + N;
    int NB = (N + 63) >> 6;                      // buckets of 64 nodes
    int chunk = (E + NBLK - 1) / NBLK;
    int ntiles = NB;

    // workspace; pairs and xsq share one region (pairs dead after bucket_csr)
    char* ws = (char*)d_ws;
    size_t off = 0;
    auto alloc = [&](size_t bytes) -> void* {
        off = (off + 255) & ~(size_t)255;
        void* p = ws + off;
        off += bytes;
        return p;
    };
    float* dinv  = (float*)alloc((size_t)N * 4);
    int*   rp    = (int*)alloc((size_t)(N + 1) * 4);
    int*   hist2 = (int*)alloc((size_t)NBLK * NB * 4);
    int*   colbase  = (int*)alloc((size_t)(NB + 1) * 4);
    int*   pairbase = (int*)alloc((size_t)(NB + 1) * 4);
    int*   col   = (int*)alloc((size_t)total * 4);
    unsigned char* W1tg = (unsigned char*)alloc(F * F * 2);
    unsigned short* xa  = (unsigned short*)alloc((size_t)N * F * 2);
    float* h2s   = (float*)alloc((size_t)N * 4);
    float* h2    = (float*)alloc((size_t)N * 4);
    size_t uniBytes = (size_t)E * 8;             // pairs
    size_t xsqBytes = (size_t)N * 32 * 4;
    if (xsqBytes > uniBytes) uniBytes = xsqBytes;
    void* uni = alloc(uniBytes);
    uint2* pairs = (uint2*)uni;
    unsigned char* xsq = (unsigned char*)uni;
    (void)ws_size;

    bucket_count<<<NBLK, 256, 0, stream>>>(dst, E, NB, chunk, hist2);
    bucket_scan<<<1, 1024, 0, stream>>>(hist2, NB, N, colbase, pairbase);
    bucket_scatter<<<NBLK, 256, 0, stream>>>(src, dst, E, NB, chunk, hist2, pairs);
    bucket_csr<<<NB, 256, 0, stream>>>(pairs, pairbase, colbase, N, E, rp, col, dinv);
    w1prep<<<(F * F + 255) / 256, 256, 0, stream>>>(W1, W1tg);
    prescale<<<(N * 32 + 255) / 256, 256, 0, stream>>>(x, dinv, xsq, N);
    agg1<<<4 * ntiles, 256, 0, stream>>>(xsq, rp, col, dinv, xa, N, ntiles);
    mlp<<<(N + 31) / 32, 512, 0, stream>>>(xa, dinv, b1, W2, W1tg, h2s, N);
    agg2<<<((size_t)N * 16 + 255) / 256, 256, 0, stream>>>(h2s, rp, col, dinv, b2, h2, N);
    edge_probs<<<(E + 255) / 256, 256, 0, stream>>>(src, dst, h2, out, E);
}

// Round 8
// 392.673 us; speedup vs baseline: 1.0438x; 1.0438x over previous
//
#include <hip/hip_runtime.h>
#include <hip/hip_bf16.h>
#include <math.h>

#define F 128
#define NBLK 256      // blocks for bucket_count / bucket_scatter
#define MAXNB 2048    // max buckets (N up to 131072 at 64 nodes/bucket)
#define CMASK 0x03FFFFFFu   // col payload mask (src id); bits 26..31 = bucket-local dst

typedef short bf16x8 __attribute__((ext_vector_type(8)));
typedef float f32x4 __attribute__((ext_vector_type(4)));
typedef float f32x2 __attribute__((ext_vector_type(2)));

__device__ __forceinline__ int rfl(int v) { return __builtin_amdgcn_readfirstlane(v); }
__device__ __forceinline__ unsigned short f2bf(float f) {
    __hip_bfloat16 h = __float2bfloat16(f);
    return *reinterpret_cast<unsigned short*>(&h);
}
__device__ __forceinline__ unsigned pack2(float lo, float hi) {
    return (unsigned)f2bf(lo) | ((unsigned)f2bf(hi) << 16);
}

// ---------------- CSR build via counting sort (zero global atomics) ----------------

// K1: per-(block,bucket) histogram. Block b owns contiguous edge chunk.
__global__ __launch_bounds__(256) void bucket_count(
    const int* __restrict__ dst, int E, int NB, int chunk, int* __restrict__ hist2)
{
    __shared__ int h[MAXNB];
    for (int j = threadIdx.x; j < NB; j += 256) h[j] = 0;
    __syncthreads();
    int b = blockIdx.x;
    int beg = b * chunk, end = min(E, beg + chunk);
    for (int e = beg + threadIdx.x; e < end; e += 256)
        atomicAdd(&h[dst[e] >> 6], 1);             // LDS atomic
    __syncthreads();
    for (int j = threadIdx.x; j < NB; j += 256) hist2[b * NB + j] = h[j];
}

// K2a: per-bucket: exclusive scan over the 256 block-counts (in place) + totals.
__global__ __launch_bounds__(256) void bucket_sumscan(
    int* __restrict__ hist2, int NB, int N,
    int* __restrict__ ptot, int* __restrict__ ctot)
{
    __shared__ int wsum[4];
    int j = blockIdx.x;
    int t = threadIdx.x;                 // = staging block b
    int v = hist2[t * NB + j];
    int lane = t & 63, w = t >> 6;
    int s = v;
#pragma unroll
    for (int off = 1; off < 64; off <<= 1) {
        int u = __shfl_up(s, off);
        if (lane >= off) s += u;
    }
    if (lane == 63) wsum[w] = s;
    __syncthreads();
    int wbase = 0;
    for (int i = 0; i < w; ++i) wbase += wsum[i];
    hist2[t * NB + j] = wbase + s - v;   // exclusive, within bucket
    if (t == 255) {
        int tot = wbase + s;
        ptot[j] = tot;
        int n0 = j << 6;
        int nodes = min(64, N - n0);
        ctot[j] = tot + nodes;           // + self-loops
    }
}

// K2b: exclusive scan of bucket totals -> pairbase / colbase.
__global__ __launch_bounds__(1024) void base_scan(
    const int* __restrict__ ptot, const int* __restrict__ ctot, int NB,
    int* __restrict__ pairbase, int* __restrict__ colbase)
{
    __shared__ int pt[MAXNB], ct[MAXNB];
    int t = threadIdx.x;
    for (int j = t; j < MAXNB; j += 1024) {
        pt[j] = (j < NB) ? ptot[j] : 0;
        ct[j] = (j < NB) ? ctot[j] : 0;
    }
    __syncthreads();
    for (int off = 1; off < MAXNB; off <<= 1) {
        int i0 = t, i1 = t + 1024;
        int a0 = (i0 >= off) ? pt[i0 - off] : 0;
        int c0 = (i0 >= off) ? ct[i0 - off] : 0;
        int a1 = (i1 >= off) ? pt[i1 - off] : 0;
        int c1 = (i1 >= off) ? ct[i1 - off] : 0;
        __syncthreads();
        pt[i0] += a0; ct[i0] += c0;
        pt[i1] += a1; ct[i1] += c1;
        __syncthreads();
    }
    for (int j = t; j < NB; j += 1024) {
        pairbase[j] = j ? pt[j - 1] : 0;
        colbase[j]  = j ? ct[j - 1] : 0;
    }
    if (t == 0) { pairbase[NB] = pt[NB - 1]; colbase[NB] = ct[NB - 1]; }
}

// K2c: hist2[b][j] += pairbase[j]  (global per-(block,bucket) scatter bases)
__global__ __launch_bounds__(256) void add_base(
    int* __restrict__ hist2, const int* __restrict__ pairbase, int NB)
{
    int j = blockIdx.x * 256 + threadIdx.x;
    if (j >= NB) return;
    hist2[blockIdx.y * NB + j] += pairbase[j];
}

// K3: scatter (src,dst) into bucket regions; ranks via LDS atomics only.
__global__ __launch_bounds__(256) void bucket_scatter(
    const int* __restrict__ src, const int* __restrict__ dst, int E, int NB, int chunk,
    const int* __restrict__ gbase2, uint2* __restrict__ pairs)
{
    __shared__ int ofs[MAXNB];
    int b = blockIdx.x;
    for (int j = threadIdx.x; j < NB; j += 256) ofs[j] = gbase2[b * NB + j];
    __syncthreads();
    int beg = b * chunk, end = min(E, beg + chunk);
    for (int e = beg + threadIdx.x; e < end; e += 256) {
        int s = src[e], d = dst[e];
        int slot = atomicAdd(&ofs[d >> 6], 1);     // LDS atomic
        pairs[slot] = make_uint2((unsigned)s, (unsigned)d);
    }
}

// K4: per-bucket node-CSR: rp, dinv, self-loop, col scatter.
// col entries carry bucket-local dst in bits 26..31.
__global__ __launch_bounds__(256) void bucket_csr(
    const uint2* __restrict__ pairs, const int* __restrict__ pairbase,
    const int* __restrict__ colbase, int N, int E,
    int* __restrict__ rp, int* __restrict__ col, float* __restrict__ dinv)
{
    __shared__ int cnt[64], fill[64], seg[64];
    int j = blockIdx.x;
    int t = threadIdx.x;
    if (t < 64) { cnt[t] = 0; fill[t] = 0; }
    __syncthreads();
    int beg = pairbase[j], end = pairbase[j + 1];
    int n0 = j << 6;
    for (int e = beg + t; e < end; e += 256)
        atomicAdd(&cnt[pairs[e].y & 63], 1);
    __syncthreads();
    if (t < 64) {
        int c = cnt[t];
        int v = c + 1;                 // + self-loop
#pragma unroll
        for (int off = 1; off < 64; off <<= 1) {
            int u = __shfl_up(v, off);
            if (t >= off) v += u;
        }
        int segb = colbase[j] + v - (c + 1);   // exclusive scan base
        int n = n0 + t;
        if (n < N) {
            seg[t] = segb;
            rp[n] = segb;
            dinv[n] = rsqrtf((float)(c + 1));
            col[segb + c] = n | (t << 26);     // tagged self-loop at segment end
            if (n == N - 1) rp[N] = segb + c + 1;
        }
    }
    __syncthreads();
    for (int e = beg + t; e < end; e += 256) {
        uint2 pr = pairs[e];
        int ln = (int)(pr.y & 63);
        int r = atomicAdd(&fill[ln], 1);       // LDS atomic
        col[seg[ln] + r] = (int)pr.x | (ln << 26);
    }
}

// ------- W1 -> bf16, transposed [j][k], XOR-swizzled bytes (once) -------
__global__ void w1prep(const float* __restrict__ W1, unsigned char* __restrict__ W1t) {
    int tid = blockIdx.x * blockDim.x + threadIdx.x;   // tid = j*128 + k
    if (tid >= F * F) return;
    int j = tid >> 7, k = tid & 127;
    unsigned short w = f2bf(W1[k * F + j]);
    int ofs = (j << 8) + (((k << 1)) ^ ((j & 7) << 4));
    *reinterpret_cast<unsigned short*>(W1t + ofs) = w;
}

// ------- prescale: xsq[p][n][32] = fp8(dinv[n]*x[n][32p..32p+31]) -------
__global__ void prescale(const float* __restrict__ x, const float* __restrict__ dinv,
                         unsigned char* __restrict__ xsq, int N) {
    int i = blockIdx.x * blockDim.x + threadIdx.x;   // float4 group: n*32+g
    if (i >= N * 32) return;
    int n = i >> 5, g = i & 31;
    int p = g >> 3, q = g & 7;
    float d = dinv[n];
    float4 v = ((const float4*)x)[i];
    int r = __builtin_amdgcn_cvt_pk_fp8_f32(v.x * d, v.y * d, 0, false);
    r = __builtin_amdgcn_cvt_pk_fp8_f32(v.z * d, v.w * d, r, true);
    *reinterpret_cast<unsigned*>(xsq + (size_t)p * N * 32 + (size_t)n * 32 + 4 * q) = r;
}

// ------- agg1 v4: edge-centric, 16-node tiles (6250 blocks/pass -> L2-resident) -------
// Pass p owns a 3.2MB xsq quarter. 32 octets split the tile's contiguous edges;
// per-octet register accumulator, flush to LDS on node change.
__global__ __launch_bounds__(256) void agg1(
    const unsigned char* __restrict__ xsq, const int* __restrict__ rp,
    const int* __restrict__ col, const float* __restrict__ dinv,
    unsigned short* __restrict__ xa, int N, int ntiles)
{
    __shared__ float acc[16 * 33];       // +1 f32 pad per node: kills bank alias
    int p = blockIdx.x / ntiles;
    int tile = blockIdx.x - p * ntiles;
    int n0 = tile << 4;                  // 16-aligned
    int nodes = min(16, N - n0);
    const unsigned char* xsp = xsq + (size_t)p * N * 32;

    for (int i = threadIdx.x; i < 16 * 33; i += 256) acc[i] = 0.f;
    __syncthreads();

    int ebase = rfl(rp[n0]);
    int eend  = rfl(rp[min(n0 + 16, N)]);
    int elen  = eend - ebase;
    int q = threadIdx.x >> 3, c8 = threadIdx.x & 7;
    int e0 = ebase + (elen * q) / 32;
    int e1 = ebase + (elen * (q + 1)) / 32;

    if (e0 < e1) {
        int cur = (int)(((unsigned)col[e0] >> 26) & 15);   // 16-aligned tile -> low 4 bits
        f32x2 a0 = {0.f, 0.f}, a1 = {0.f, 0.f};
        for (int e = e0; e < e1; ++e) {
            unsigned cv = (unsigned)col[e];
            int nd = (int)((cv >> 26) & 15);
            if (nd != cur) {
                int b = cur * 33 + 4 * c8;
                atomicAdd(&acc[b + 0], a0.x);
                atomicAdd(&acc[b + 1], a0.y);
                atomicAdd(&acc[b + 2], a1.x);
                atomicAdd(&acc[b + 3], a1.y);
                a0 = {0.f, 0.f}; a1 = {0.f, 0.f};
                cur = nd;
            }
            unsigned s = cv & CMASK;
            unsigned u = *reinterpret_cast<const unsigned*>(xsp + (size_t)s * 32 + 4 * c8);
            a0 += __builtin_amdgcn_cvt_pk_f32_fp8(u, false);
            a1 += __builtin_amdgcn_cvt_pk_f32_fp8(u, true);
        }
        int b = cur * 33 + 4 * c8;
        atomicAdd(&acc[b + 0], a0.x);
        atomicAdd(&acc[b + 1], a0.y);
        atomicAdd(&acc[b + 2], a1.x);
        atomicAdd(&acc[b + 3], a1.y);
    }
    __syncthreads();

    // epilogue: thread t<64 -> node t>>2, 8 feats; scale by dinv, pack bf16, 16B store
    int nd = threadIdx.x >> 2, fq = threadIdx.x & 3;
    if (nd < nodes) {
        float d = dinv[n0 + nd];
        const float* ap = &acc[nd * 33 + 8 * fq];
        unsigned u0 = pack2(ap[0] * d, ap[1] * d);
        unsigned u1 = pack2(ap[2] * d, ap[3] * d);
        unsigned u2 = pack2(ap[4] * d, ap[5] * d);
        unsigned u3 = pack2(ap[6] * d, ap[7] * d);
        *reinterpret_cast<uint4*>(xa + (size_t)(n0 + nd) * F + p * 32 + 8 * fq) =
            make_uint4(u0, u1, u2, u3);
    }
}

// ------- MLP: h2s[i] = dinv_i * (relu(xa@W1 + b1) @ W2) via MFMA -------
__global__ __launch_bounds__(512) void mlp(
    const unsigned short* __restrict__ xa, const float* __restrict__ dinv,
    const float* __restrict__ b1, const float* __restrict__ W2,
    const unsigned char* __restrict__ W1t_g, float* __restrict__ h2s, int N)
{
    __shared__ unsigned char W1t[F * F * 2];   // 32 KB swizzled [j][k]
    __shared__ unsigned char XA[32 * 256];     // 8 KB swizzled [node][k]
    __shared__ float part[2][16][4];

    for (int idx = threadIdx.x; idx < (F * F * 2) / 16; idx += 512)
        ((int4*)W1t)[idx] = ((const int4*)W1t_g)[idx];

    {
        int r = threadIdx.x >> 4, t16 = threadIdx.x & 15;
        int gi = blockIdx.x * 32 + r;
        uint4 v = make_uint4(0, 0, 0, 0);
        if (gi < N) v = *reinterpret_cast<const uint4*>(xa + (size_t)gi * F + 8 * t16);
        *reinterpret_cast<uint4*>(XA + r * 256 + ((16 * t16) ^ ((r & 7) << 4))) = v;
    }
    __syncthreads();

    int wave = threadIdx.x >> 6, lane = threadIdx.x & 63;
    int g = wave >> 2, jt0 = (wave & 3) * 2;
    int l15 = lane & 15;
    int kb = (lane >> 4) * 16;

    bf16x8 afr[4];
    int arow = g * 16 + l15;
#pragma unroll
    for (int kk = 0; kk < 4; ++kk) {
        int ofs = arow * 256 + ((kk * 64 + kb) ^ ((arow & 7) << 4));
        afr[kk] = *reinterpret_cast<const bf16x8*>(XA + ofs);
    }

    float p[4] = {0.f, 0.f, 0.f, 0.f};
#pragma unroll
    for (int jj = 0; jj < 2; ++jj) {
        int j = (jt0 + jj) * 16 + l15;
        f32x4 d = {0.f, 0.f, 0.f, 0.f};
#pragma unroll
        for (int kk = 0; kk < 4; ++kk) {
            int ofs = j * 256 + ((kk * 64 + kb) ^ ((j & 7) << 4));
            bf16x8 bfr = *reinterpret_cast<const bf16x8*>(W1t + ofs);
            d = __builtin_amdgcn_mfma_f32_16x16x32_bf16(afr[kk], bfr, d, 0, 0, 0);
        }
        float bj = b1[j], wj = W2[j];
#pragma unroll
        for (int r = 0; r < 4; ++r) {
            float v = fmaxf(d[r] + bj, 0.f);
            p[r] += v * wj;
        }
    }
#pragma unroll
    for (int r = 0; r < 4; ++r) {
        p[r] += __shfl_xor(p[r], 1);
        p[r] += __shfl_xor(p[r], 2);
        p[r] += __shfl_xor(p[r], 4);
        p[r] += __shfl_xor(p[r], 8);
    }
    if (l15 == 0) {
#pragma unroll
        for (int r = 0; r < 4; ++r)
            part[g][(lane >> 4) * 4 + r][wave & 3] = p[r];
    }
    __syncthreads();

    if (threadIdx.x < 32) {
        int i = blockIdx.x * 32 + threadIdx.x;
        if (i < N) {
            const float* q = part[threadIdx.x >> 4][threadIdx.x & 15];
            h2s[i] = dinv[i] * (q[0] + q[1] + q[2] + q[3]);
        }
    }
}

// ------- layer 2 aggregation: quarter-wave (16 lanes) per node -------
__global__ __launch_bounds__(256) void agg2(
    const float* __restrict__ h2s, const int* __restrict__ rp,
    const int* __restrict__ col, const float* __restrict__ dinv,
    const float* __restrict__ b2, float* __restrict__ h2, int N)
{
    int nid = (blockIdx.x * 256 + threadIdx.x) >> 4;
    int c = threadIdx.x & 15;
    if (nid >= N) return;
    int beg = rfl(rp[nid]);
    int end = rfl(rp[nid + 1]);
    float s = 0.f;
    for (int e = beg + c; e < end; e += 16)
        s += h2s[col[e] & CMASK];
#pragma unroll
    for (int off = 8; off; off >>= 1) s += __shfl_xor(s, off);
    if (c == 0) h2[nid] = dinv[nid] * s + b2[0];
}

// ------- edge probabilities -------
__global__ void edge_probs(const int* __restrict__ src, const int* __restrict__ dst,
                           const float* __restrict__ h2, float* __restrict__ out, int E) {
    int e = blockIdx.x * blockDim.x + threadIdx.x;
    if (e >= E) return;
    float v = h2[src[e]] * h2[dst[e]];
    out[e] = 1.0f / (1.0f + __expf(-v));
}

// ---------------- launch ----------------

extern "C" void kernel_launch(void* const* d_in, const int* in_sizes, int n_in,
                              void* d_out, int out_size, void* d_ws, size_t ws_size,
                              hipStream_t stream) {
    const float* x  = (const float*)d_in[0];
    const int*   ei = (const int*)d_in[1];       // int32 (JAX x64 disabled)
    const float* W1 = (const float*)d_in[2];
    const float* b1 = (const float*)d_in[3];
    const float* W2 = (const float*)d_in[4];
    const float* b2 = (const float*)d_in[5];
    float* out = (float*)d_out;

    int N = in_sizes[0] / F;
    int E = in_sizes[1] / 2;
    const int* src = ei;
    const int* dst = ei + E;
    int total = E + N;
    int NB = (N + 63) >> 6;                      // buckets of 64 nodes (CSR build)
    int chunk = (E + NBLK - 1) / NBLK;
    int ntiles = (N + 15) >> 4;                  // agg1 tiles of 16 nodes

    // workspace; pairs and xsq share one region (pairs dead after bucket_csr)
    char* ws = (char*)d_ws;
    size_t off = 0;
    auto alloc = [&](size_t bytes) -> void* {
        off = (off + 255) & ~(size_t)255;
        void* p = ws + off;
        off += bytes;
        return p;
    };
    float* dinv  = (float*)alloc((size_t)N * 4);
    int*   rp    = (int*)alloc((size_t)(N + 1) * 4);
    int*   hist2 = (int*)alloc((size_t)NBLK * NB * 4);
    int*   colbase  = (int*)alloc((size_t)(NB + 1) * 4);
    int*   pairbase = (int*)alloc((size_t)(NB + 1) * 4);
    int*   ptot  = (int*)alloc((size_t)NB * 4);
    int*   ctot  = (int*)alloc((size_t)NB * 4);
    int*   col   = (int*)alloc((size_t)total * 4);
    unsigned char* W1tg = (unsigned char*)alloc(F * F * 2);
    unsigned short* xa  = (unsigned short*)alloc((size_t)N * F * 2);
    float* h2s   = (float*)alloc((size_t)N * 4);
    float* h2    = (float*)alloc((size_t)N * 4);
    size_t uniBytes = (size_t)E * 8;             // pairs
    size_t xsqBytes = (size_t)N * 32 * 4;
    if (xsqBytes > uniBytes) uniBytes = xsqBytes;
    void* uni = alloc(uniBytes);
    uint2* pairs = (uint2*)uni;
    unsigned char* xsq = (unsigned char*)uni;
    (void)ws_size;

    bucket_count<<<NBLK, 256, 0, stream>>>(dst, E, NB, chunk, hist2);
    bucket_sumscan<<<NB, 256, 0, stream>>>(hist2, NB, N, ptot, ctot);
    base_scan<<<1, 1024, 0, stream>>>(ptot, ctot, NB, pairbase, colbase);
    add_base<<<dim3((NB + 255) / 256, NBLK), 256, 0, stream>>>(hist2, pairbase, NB);
    bucket_scatter<<<NBLK, 256, 0, stream>>>(src, dst, E, NB, chunk, hist2, pairs);
    bucket_csr<<<NB, 256, 0, stream>>>(pairs, pairbase, colbase, N, E, rp, col, dinv);
    w1prep<<<(F * F + 255) / 256, 256, 0, stream>>>(W1, W1tg);
    prescale<<<(N * 32 + 255) / 256, 256, 0, stream>>>(x, dinv, xsq, N);
    agg1<<<4 * ntiles, 256, 0, stream>>>(xsq, rp, col, dinv, xa, N, ntiles);
    mlp<<<(N + 31) / 32, 512, 0, stream>>>(xa, dinv, b1, W2, W1tg, h2s, N);
    agg2<<<((size_t)N * 16 + 255) / 256, 256, 0, stream>>>(h2s, rp, col, dinv, b2, h2, N);
    edge_probs<<<(E + 255) / 256, 256, 0, stream>>>(src, dst, h2, out, E);
}

// Round 9
// 247.530 us; speedup vs baseline: 1.6559x; 1.5864x over previous
//
#include <hip/hip_runtime.h>
#include <hip/hip_bf16.h>
#include <math.h>

#define F 128
#define NBLK 256      // blocks for bucket_count / bucket_scatter
#define MAXNB 2048    // max buckets (N up to 131072 at 64 nodes/bucket)
#define CMASK 0x03FFFFFFu   // col payload mask (src id); bits 26..31 = bucket-local dst

typedef short bf16x8 __attribute__((ext_vector_type(8)));
typedef float f32x4 __attribute__((ext_vector_type(4)));
typedef float f32x2 __attribute__((ext_vector_type(2)));

__device__ __forceinline__ int rfl(int v) { return __builtin_amdgcn_readfirstlane(v); }
__device__ __forceinline__ unsigned short f2bf(float f) {
    __hip_bfloat16 h = __float2bfloat16(f);
    return *reinterpret_cast<unsigned short*>(&h);
}
__device__ __forceinline__ unsigned pack2(float lo, float hi) {
    return (unsigned)f2bf(lo) | ((unsigned)f2bf(hi) << 16);
}

// ---------------- CSR build via counting sort (zero global atomics) ----------------

// K1: per-(block,bucket) histogram. Block b owns contiguous edge chunk.
__global__ __launch_bounds__(256) void bucket_count(
    const int* __restrict__ dst, int E, int NB, int chunk, int* __restrict__ hist2)
{
    __shared__ int h[MAXNB];
    for (int j = threadIdx.x; j < NB; j += 256) h[j] = 0;
    __syncthreads();
    int b = blockIdx.x;
    int beg = b * chunk, end = min(E, beg + chunk);
    for (int e = beg + threadIdx.x; e < end; e += 256)
        atomicAdd(&h[dst[e] >> 6], 1);             // LDS atomic
    __syncthreads();
    for (int j = threadIdx.x; j < NB; j += 256) hist2[b * NB + j] = h[j];
}

// K2a: per-bucket: exclusive scan over the 256 block-counts (in place) + totals.
__global__ __launch_bounds__(256) void bucket_sumscan(
    int* __restrict__ hist2, int NB, int N,
    int* __restrict__ ptot, int* __restrict__ ctot)
{
    __shared__ int wsum[4];
    int j = blockIdx.x;
    int t = threadIdx.x;                 // = staging block b
    int v = hist2[t * NB + j];
    int lane = t & 63, w = t >> 6;
    int s = v;
#pragma unroll
    for (int off = 1; off < 64; off <<= 1) {
        int u = __shfl_up(s, off);
        if (lane >= off) s += u;
    }
    if (lane == 63) wsum[w] = s;
    __syncthreads();
    int wbase = 0;
    for (int i = 0; i < w; ++i) wbase += wsum[i];
    hist2[t * NB + j] = wbase + s - v;   // exclusive, within bucket
    if (t == 255) {
        int tot = wbase + s;
        ptot[j] = tot;
        int n0 = j << 6;
        int nodes = min(64, N - n0);
        ctot[j] = tot + nodes;           // + self-loops
    }
}

// K2b: exclusive scan of bucket totals -> pairbase / colbase.
__global__ __launch_bounds__(1024) void base_scan(
    const int* __restrict__ ptot, const int* __restrict__ ctot, int NB,
    int* __restrict__ pairbase, int* __restrict__ colbase)
{
    __shared__ int pt[MAXNB], ct[MAXNB];
    int t = threadIdx.x;
    for (int j = t; j < MAXNB; j += 1024) {
        pt[j] = (j < NB) ? ptot[j] : 0;
        ct[j] = (j < NB) ? ctot[j] : 0;
    }
    __syncthreads();
    for (int off = 1; off < MAXNB; off <<= 1) {
        int i0 = t, i1 = t + 1024;
        int a0 = (i0 >= off) ? pt[i0 - off] : 0;
        int c0 = (i0 >= off) ? ct[i0 - off] : 0;
        int a1 = (i1 >= off) ? pt[i1 - off] : 0;
        int c1 = (i1 >= off) ? ct[i1 - off] : 0;
        __syncthreads();
        pt[i0] += a0; ct[i0] += c0;
        pt[i1] += a1; ct[i1] += c1;
        __syncthreads();
    }
    for (int j = t; j < NB; j += 1024) {
        pairbase[j] = j ? pt[j - 1] : 0;
        colbase[j]  = j ? ct[j - 1] : 0;
    }
    if (t == 0) { pairbase[NB] = pt[NB - 1]; colbase[NB] = ct[NB - 1]; }
}

// K2c: hist2[b][j] += pairbase[j]
__global__ __launch_bounds__(256) void add_base(
    int* __restrict__ hist2, const int* __restrict__ pairbase, int NB)
{
    int j = blockIdx.x * 256 + threadIdx.x;
    if (j >= NB) return;
    hist2[blockIdx.y * NB + j] += pairbase[j];
}

// K3: scatter tagged (src | localdst<<26) into bucket regions (4B entries).
__global__ __launch_bounds__(256) void bucket_scatter(
    const int* __restrict__ src, const int* __restrict__ dst, int E, int NB, int chunk,
    const int* __restrict__ gbase2, unsigned* __restrict__ pairs)
{
    __shared__ int ofs[MAXNB];
    int b = blockIdx.x;
    for (int j = threadIdx.x; j < NB; j += 256) ofs[j] = gbase2[b * NB + j];
    __syncthreads();
    int beg = b * chunk, end = min(E, beg + chunk);
    for (int e = beg + threadIdx.x; e < end; e += 256) {
        int s = src[e], d = dst[e];
        int slot = atomicAdd(&ofs[d >> 6], 1);     // LDS atomic
        pairs[slot] = (unsigned)s | ((unsigned)(d & 63) << 26);
    }
}

// K4: per-bucket node-CSR: rp, dinv, self-loop, col scatter (entries copied verbatim).
__global__ __launch_bounds__(256) void bucket_csr(
    const unsigned* __restrict__ pairs, const int* __restrict__ pairbase,
    const int* __restrict__ colbase, int N, int E,
    int* __restrict__ rp, unsigned* __restrict__ col, float* __restrict__ dinv)
{
    __shared__ int cnt[64], fill[64], seg[64];
    int j = blockIdx.x;
    int t = threadIdx.x;
    if (t < 64) { cnt[t] = 0; fill[t] = 0; }
    __syncthreads();
    int beg = pairbase[j], end = pairbase[j + 1];
    int n0 = j << 6;
    for (int e = beg + t; e < end; e += 256)
        atomicAdd(&cnt[pairs[e] >> 26], 1);
    __syncthreads();
    if (t < 64) {
        int c = cnt[t];
        int v = c + 1;                 // + self-loop
#pragma unroll
        for (int off = 1; off < 64; off <<= 1) {
            int u = __shfl_up(v, off);
            if (t >= off) v += u;
        }
        int segb = colbase[j] + v - (c + 1);   // exclusive scan base
        int n = n0 + t;
        if (n < N) {
            seg[t] = segb;
            rp[n] = segb;
            dinv[n] = rsqrtf((float)(c + 1));
            col[segb + c] = (unsigned)n | ((unsigned)t << 26);  // self-loop at end
            if (n == N - 1) rp[N] = segb + c + 1;
        }
    }
    __syncthreads();
    for (int e = beg + t; e < end; e += 256) {
        unsigned pr = pairs[e];
        int ln = (int)(pr >> 26);
        int r = atomicAdd(&fill[ln], 1);       // LDS atomic
        col[seg[ln] + r] = pr;
    }
}

// ------- W1 -> bf16, transposed [j][k], XOR-swizzled bytes (once) -------
__global__ void w1prep(const float* __restrict__ W1, unsigned char* __restrict__ W1t) {
    int tid = blockIdx.x * blockDim.x + threadIdx.x;   // tid = j*128 + k
    if (tid >= F * F) return;
    int j = tid >> 7, k = tid & 127;
    unsigned short w = f2bf(W1[k * F + j]);
    int ofs = (j << 8) + (((k << 1)) ^ ((j & 7) << 4));
    *reinterpret_cast<unsigned short*>(W1t + ofs) = w;
}

// ------- prescale: xsq[p][n][32] = fp8(dinv[n]*x[n][32p..32p+31]) -------
__global__ void prescale(const float* __restrict__ x, const float* __restrict__ dinv,
                         unsigned char* __restrict__ xsq, int N) {
    int i = blockIdx.x * blockDim.x + threadIdx.x;   // float4 group: n*32+g
    if (i >= N * 32) return;
    int n = i >> 5, g = i & 31;
    int p = g >> 3, q = g & 7;
    float d = dinv[n];
    float4 v = ((const float4*)x)[i];
    int r = __builtin_amdgcn_cvt_pk_fp8_f32(v.x * d, v.y * d, 0, false);
    r = __builtin_amdgcn_cvt_pk_fp8_f32(v.z * d, v.w * d, r, true);
    *reinterpret_cast<unsigned*>(xsq + (size_t)p * N * 32 + (size_t)n * 32 + 4 * q) = r;
}

// ------- agg1 v5: node-centric octet walk, zero LDS, 4-deep pipelined gathers -------
// Pass p owns a 3.2MB xsq quarter (16-node blocks, 6250/pass -> L2-resident).
// Octet (8 lanes) owns HALF of one node's edge list; 4 feats/lane in VGPRs;
// halves combine via shfl_xor(32); direct bf16 store to xa. No LDS, no atomics.
__global__ __launch_bounds__(256, 4) void agg1(
    const unsigned char* __restrict__ xsq, const int* __restrict__ rp,
    const unsigned* __restrict__ col, const float* __restrict__ dinv,
    unsigned short* __restrict__ xa, int N, int ntiles)
{
    int p = blockIdx.x / ntiles;
    int tile = blockIdx.x - p * ntiles;
    int w = threadIdx.x >> 6, l = threadIdx.x & 63;
    int o = l >> 3, c8 = l & 7;
    int half = o >> 2;
    int node = tile * 16 + w * 4 + (o & 3);
    const unsigned char* xsp = xsq + (size_t)p * N * 32;

    bool valid = node < N;
    int beg = valid ? rp[node] : 0;
    int end = valid ? rp[node + 1] : 0;
    int deg = end - beg;
    int h0 = (deg + 1) >> 1;
    int myBeg = beg + half * h0;
    int myCnt = half ? (deg - h0) : h0;

    float a0 = 0.f, a1 = 0.f, a2 = 0.f, a3 = 0.f;
    const unsigned* cp = col + myBeg;
    int k = 0;
    for (; k + 4 <= myCnt; k += 4) {
        unsigned cv0 = cp[k], cv1 = cp[k + 1], cv2 = cp[k + 2], cv3 = cp[k + 3];
        unsigned u0 = *reinterpret_cast<const unsigned*>(xsp + (size_t)(cv0 & CMASK) * 32 + 4 * c8);
        unsigned u1 = *reinterpret_cast<const unsigned*>(xsp + (size_t)(cv1 & CMASK) * 32 + 4 * c8);
        unsigned u2 = *reinterpret_cast<const unsigned*>(xsp + (size_t)(cv2 & CMASK) * 32 + 4 * c8);
        unsigned u3 = *reinterpret_cast<const unsigned*>(xsp + (size_t)(cv3 & CMASK) * 32 + 4 * c8);
        f32x2 p0 = __builtin_amdgcn_cvt_pk_f32_fp8(u0, false);
        f32x2 q0 = __builtin_amdgcn_cvt_pk_f32_fp8(u0, true);
        f32x2 p1 = __builtin_amdgcn_cvt_pk_f32_fp8(u1, false);
        f32x2 q1 = __builtin_amdgcn_cvt_pk_f32_fp8(u1, true);
        f32x2 p2 = __builtin_amdgcn_cvt_pk_f32_fp8(u2, false);
        f32x2 q2 = __builtin_amdgcn_cvt_pk_f32_fp8(u2, true);
        f32x2 p3 = __builtin_amdgcn_cvt_pk_f32_fp8(u3, false);
        f32x2 q3 = __builtin_amdgcn_cvt_pk_f32_fp8(u3, true);
        a0 += p0.x + p1.x + p2.x + p3.x;
        a1 += p0.y + p1.y + p2.y + p3.y;
        a2 += q0.x + q1.x + q2.x + q3.x;
        a3 += q0.y + q1.y + q2.y + q3.y;
    }
    for (; k < myCnt; ++k) {
        unsigned cv = cp[k];
        unsigned u = *reinterpret_cast<const unsigned*>(xsp + (size_t)(cv & CMASK) * 32 + 4 * c8);
        f32x2 pp = __builtin_amdgcn_cvt_pk_f32_fp8(u, false);
        f32x2 qq = __builtin_amdgcn_cvt_pk_f32_fp8(u, true);
        a0 += pp.x; a1 += pp.y; a2 += qq.x; a3 += qq.y;
    }

    a0 += __shfl_xor(a0, 32);
    a1 += __shfl_xor(a1, 32);
    a2 += __shfl_xor(a2, 32);
    a3 += __shfl_xor(a3, 32);

    if (half == 0 && valid) {
        float d = dinv[node];
        unsigned q0 = pack2(a0 * d, a1 * d);
        unsigned q1 = pack2(a2 * d, a3 * d);
        *reinterpret_cast<uint2*>(xa + (size_t)node * F + p * 32 + 4 * c8) =
            make_uint2(q0, q1);
    }
}

// ------- MLP: h2s[i] = dinv_i * (relu(xa@W1 + b1) @ W2) via MFMA -------
__global__ __launch_bounds__(512) void mlp(
    const unsigned short* __restrict__ xa, const float* __restrict__ dinv,
    const float* __restrict__ b1, const float* __restrict__ W2,
    const unsigned char* __restrict__ W1t_g, float* __restrict__ h2s, int N)
{
    __shared__ unsigned char W1t[F * F * 2];   // 32 KB swizzled [j][k]
    __shared__ unsigned char XA[32 * 256];     // 8 KB swizzled [node][k]
    __shared__ float part[2][16][4];

    for (int idx = threadIdx.x; idx < (F * F * 2) / 16; idx += 512)
        ((int4*)W1t)[idx] = ((const int4*)W1t_g)[idx];

    {
        int r = threadIdx.x >> 4, t16 = threadIdx.x & 15;
        int gi = blockIdx.x * 32 + r;
        uint4 v = make_uint4(0, 0, 0, 0);
        if (gi < N) v = *reinterpret_cast<const uint4*>(xa + (size_t)gi * F + 8 * t16);
        *reinterpret_cast<uint4*>(XA + r * 256 + ((16 * t16) ^ ((r & 7) << 4))) = v;
    }
    __syncthreads();

    int wave = threadIdx.x >> 6, lane = threadIdx.x & 63;
    int g = wave >> 2, jt0 = (wave & 3) * 2;
    int l15 = lane & 15;
    int kb = (lane >> 4) * 16;

    bf16x8 afr[4];
    int arow = g * 16 + l15;
#pragma unroll
    for (int kk = 0; kk < 4; ++kk) {
        int ofs = arow * 256 + ((kk * 64 + kb) ^ ((arow & 7) << 4));
        afr[kk] = *reinterpret_cast<const bf16x8*>(XA + ofs);
    }

    float p[4] = {0.f, 0.f, 0.f, 0.f};
#pragma unroll
    for (int jj = 0; jj < 2; ++jj) {
        int j = (jt0 + jj) * 16 + l15;
        f32x4 d = {0.f, 0.f, 0.f, 0.f};
#pragma unroll
        for (int kk = 0; kk < 4; ++kk) {
            int ofs = j * 256 + ((kk * 64 + kb) ^ ((j & 7) << 4));
            bf16x8 bfr = *reinterpret_cast<const bf16x8*>(W1t + ofs);
            d = __builtin_amdgcn_mfma_f32_16x16x32_bf16(afr[kk], bfr, d, 0, 0, 0);
        }
        float bj = b1[j], wj = W2[j];
#pragma unroll
        for (int r = 0; r < 4; ++r) {
            float v = fmaxf(d[r] + bj, 0.f);
            p[r] += v * wj;
        }
    }
#pragma unroll
    for (int r = 0; r < 4; ++r) {
        p[r] += __shfl_xor(p[r], 1);
        p[r] += __shfl_xor(p[r], 2);
        p[r] += __shfl_xor(p[r], 4);
        p[r] += __shfl_xor(p[r], 8);
    }
    if (l15 == 0) {
#pragma unroll
        for (int r = 0; r < 4; ++r)
            part[g][(lane >> 4) * 4 + r][wave & 3] = p[r];
    }
    __syncthreads();

    if (threadIdx.x < 32) {
        int i = blockIdx.x * 32 + threadIdx.x;
        if (i < N) {
            const float* q = part[threadIdx.x >> 4][threadIdx.x & 15];
            h2s[i] = dinv[i] * (q[0] + q[1] + q[2] + q[3]);
        }
    }
}

// ------- layer 2 aggregation: quarter-wave (16 lanes) per node -------
__global__ __launch_bounds__(256) void agg2(
    const float* __restrict__ h2s, const int* __restrict__ rp,
    const unsigned* __restrict__ col, const float* __restrict__ dinv,
    const float* __restrict__ b2, float* __restrict__ h2, int N)
{
    int nid = (blockIdx.x * 256 + threadIdx.x) >> 4;
    int c = threadIdx.x & 15;
    if (nid >= N) return;
    int beg = rfl(rp[nid]);
    int end = rfl(rp[nid + 1]);
    float s = 0.f;
    for (int e = beg + c; e < end; e += 16)
        s += h2s[col[e] & CMASK];
#pragma unroll
    for (int off = 8; off; off >>= 1) s += __shfl_xor(s, off);
    if (c == 0) h2[nid] = dinv[nid] * s + b2[0];
}

// ------- edge probabilities -------
__global__ void edge_probs(const int* __restrict__ src, const int* __restrict__ dst,
                           const float* __restrict__ h2, float* __restrict__ out, int E) {
    int e = blockIdx.x * blockDim.x + threadIdx.x;
    if (e >= E) return;
    float v = h2[src[e]] * h2[dst[e]];
    out[e] = 1.0f / (1.0f + __expf(-v));
}

// ---------------- launch ----------------

extern "C" void kernel_launch(void* const* d_in, const int* in_sizes, int n_in,
                              void* d_out, int out_size, void* d_ws, size_t ws_size,
                              hipStream_t stream) {
    const float* x  = (const float*)d_in[0];
    const int*   ei = (const int*)d_in[1];       // int32 (JAX x64 disabled)
    const float* W1 = (const float*)d_in[2];
    const float* b1 = (const float*)d_in[3];
    const float* W2 = (const float*)d_in[4];
    const float* b2 = (const float*)d_in[5];
    float* out = (float*)d_out;

    int N = in_sizes[0] / F;
    int E = in_sizes[1] / 2;
    const int* src = ei;
    const int* dst = ei + E;
    int total = E + N;
    int NB = (N + 63) >> 6;                      // buckets of 64 nodes (CSR build)
    int chunk = (E + NBLK - 1) / NBLK;
    int ntiles = (N + 15) >> 4;                  // agg1 tiles of 16 nodes

    // workspace; pairs (4B/edge) and xsq share one region
    char* ws = (char*)d_ws;
    size_t off = 0;
    auto alloc = [&](size_t bytes) -> void* {
        off = (off + 255) & ~(size_t)255;
        void* p = ws + off;
        off += bytes;
        return p;
    };
    float* dinv  = (float*)alloc((size_t)N * 4);
    int*   rp    = (int*)alloc((size_t)(N + 1) * 4);
    int*   hist2 = (int*)alloc((size_t)NBLK * NB * 4);
    int*   colbase  = (int*)alloc((size_t)(NB + 1) * 4);
    int*   pairbase = (int*)alloc((size_t)(NB + 1) * 4);
    int*   ptot  = (int*)alloc((size_t)NB * 4);
    int*   ctot  = (int*)alloc((size_t)NB * 4);
    unsigned* col = (unsigned*)alloc((size_t)total * 4);
    unsigned char* W1tg = (unsigned char*)alloc(F * F * 2);
    unsigned short* xa  = (unsigned short*)alloc((size_t)N * F * 2);
    float* h2s   = (float*)alloc((size_t)N * 4);
    float* h2    = (float*)alloc((size_t)N * 4);
    size_t uniBytes = (size_t)E * 4;             // pairs (tagged, 4B)
    size_t xsqBytes = (size_t)N * 32 * 4;
    if (xsqBytes > uniBytes) uniBytes = xsqBytes;
    void* uni = alloc(uniBytes);
    unsigned* pairs = (unsigned*)uni;
    unsigned char* xsq = (unsigned char*)uni;
    (void)ws_size;

    bucket_count<<<NBLK, 256, 0, stream>>>(dst, E, NB, chunk, hist2);
    bucket_sumscan<<<NB, 256, 0, stream>>>(hist2, NB, N, ptot, ctot);
    base_scan<<<1, 1024, 0, stream>>>(ptot, ctot, NB, pairbase, colbase);
    add_base<<<dim3((NB + 255) / 256, NBLK), 256, 0, stream>>>(hist2, pairbase, NB);
    bucket_scatter<<<NBLK, 256, 0, stream>>>(src, dst, E, NB, chunk, hist2, pairs);
    bucket_csr<<<NB, 256, 0, stream>>>(pairs, pairbase, colbase, N, E, rp, col, dinv);
    w1prep<<<(F * F + 255) / 256, 256, 0, stream>>>(W1, W1tg);
    prescale<<<(N * 32 + 255) / 256, 256, 0, stream>>>(x, dinv, xsq, N);
    agg1<<<4 * ntiles, 256, 0, stream>>>(xsq, rp, col, dinv, xa, N, ntiles);
    mlp<<<(N + 31) / 32, 512, 0, stream>>>(xa, dinv, b1, W2, W1tg, h2s, N);
    agg2<<<((size_t)N * 16 + 255) / 256, 256, 0, stream>>>(h2s, rp, col, dinv, b2, h2, N);
    edge_probs<<<(E + 255) / 256, 256, 0, stream>>>(src, dst, h2, out, E);
}